// Round 3
// baseline (257.611 us; speedup 1.0000x reference)
//
#include <hip/hip_runtime.h>
#include <hip/hip_bf16.h>

#define NNODE 1024
#define DIM 128
#define HEADS 8
#define DK 16
#define EDIM 16
#define BN 8               // target nodes per attn block
#define MR 16              // source rows per chunk
#define NCH 8              // chunks per block -> 128 source rows per block
#define NGRP 8             // m-group blocks per target row (1024/(MR*NCH))
#define KV_ROW 160         // k/v LDS row stride dwords = 8 h * 20
#define H_STRIDE 20        // 20h mod 32 distinct for h=0..7 -> conflict-free reads
#define EF_ROW 20          // ef m-stride (dwords)
#define EF_NSTR 324        // ef n-stride = 16*20+4: 324 mod 32 = 4 -> skewed banks
#define MK_STR 17
#define LOG2E 1.44269504f

// per-buffer layout (floats): ef [0,2592) | kv [2592,7712) | mk ints [7712,7848)
// two ping-pong buffers; reduction scratch overlays [0,8448) after compute loop.
#define BUF 7848
#define SMEM_F (2 * BUF)   // 15696 f = 62784 B -> 2 blocks/CU (VGPRs force 2 anyway)
#define KV_OFF 2592
#define MK_OFF 7712

// ---------------- Kernel 1: LayerNorm + QKV projection ----------------
__global__ __launch_bounds__(384)
void ln_qkv_kernel(const float* __restrict__ x,
                   const float* __restrict__ Wq, const float* __restrict__ bq,
                   const float* __restrict__ Wk, const float* __restrict__ bk,
                   const float* __restrict__ Wv, const float* __restrict__ bv,
                   const float* __restrict__ gamma, const float* __restrict__ beta,
                   float* __restrict__ qg, float* __restrict__ kg, float* __restrict__ vg) {
    const int n = blockIdx.x;
    const int t = threadIdx.x;
    __shared__ float hrow[DIM];
    __shared__ float part[4];

    float xv = 0.f;
    if (t < 128) {
        xv = x[n * DIM + t];
        float v = xv;
        #pragma unroll
        for (int off = 32; off >= 1; off >>= 1) v += __shfl_xor(v, off);
        if ((t & 63) == 0) part[t >> 6] = v;
    }
    __syncthreads();
    const float mu = (part[0] + part[1]) * (1.0f / DIM);
    const float dx = xv - mu;
    if (t < 128) {
        float v = dx * dx;
        #pragma unroll
        for (int off = 32; off >= 1; off >>= 1) v += __shfl_xor(v, off);
        if ((t & 63) == 0) part[2 + (t >> 6)] = v;
    }
    __syncthreads();
    if (t < 128) {
        const float var = (part[2] + part[3]) * (1.0f / DIM);
        hrow[t] = dx * rsqrtf(var + 1e-5f) * gamma[t] + beta[t];
    }
    __syncthreads();

    const int which = t >> 7;          // 0,1,2 -> q,k,v (wave-uniform)
    const int col = t & 127;
    const float* W = (which == 0) ? Wq : (which == 1) ? Wk : Wv;
    const float* b = (which == 0) ? bq : (which == 1) ? bk : bv;
    float* o       = (which == 0) ? qg : (which == 1) ? kg : vg;
    float a0 = b[col], a1 = 0.f;       // dual accumulators: break 128-deep dep chain
    #pragma unroll 8
    for (int i = 0; i < DIM; i += 2) {
        a0 = fmaf(hrow[i],     W[i * DIM + col],       a0);
        a1 = fmaf(hrow[i + 1], W[(i + 1) * DIM + col], a1);
    }
    o[n * DIM + col] = a0 + a1;
}

// ---------------- Kernel 2: double-buffered chunked attention ----------------
// grid = (1024/BN) * NGRP = 1024 blocks; 256 threads.
// Round-2 lesson: 116 VGPR -> 2 waves/EU on this chip (19% occ regardless of LDS);
// the 64-VGPR config that gives 4 waves/EU spills this kernel. So instead of
// chasing occupancy, hide latency IN-WAVE: ping-pong LDS buffers, issue chunk
// c+1 global loads into regs BEFORE compute of chunk c, ds_write AFTER (T14),
// ONE barrier per chunk. Staging regs (+~25 VGPR) keep us in the same
// 129-256 VGPR occupancy band -> no occupancy cost.
// Thread map: s = t>>5, np = (t>>3)&3, h = t&7; thread handles n = np, np+4.
// ALL register-array indices remain compile-time constants.
__global__ __launch_bounds__(256, 2)
void attn_kernel(const float* __restrict__ qg, const float* __restrict__ kg,
                 const float* __restrict__ vg, const float* __restrict__ ef,
                 const int* __restrict__ mask,
                 const float* __restrict__ Wae, const float* __restrict__ bae,
                 float* __restrict__ acc) {
    const int t = threadIdx.x;
    const int s  = t >> 5;        // 0..7 m sub-slot
    const int np = (t >> 3) & 3;  // n-pair id
    const int h  = t & 7;         // head
    const int wid = t >> 6, lane = t & 63;
    const int bx = blockIdx.x;
    const int n0  = (bx >> 3) * BN;
    const int grp = bx & 7;
    const int mb0 = grp * (MR * NCH);        // m-group: 128 consecutive source rows

    __shared__ float smem[SMEM_F];           // 62784 B, two ping-pong buffers

    // --- per-thread constants (global, L2-hot) ---
    float qreg[2][DK];
    #pragma unroll
    for (int hf = 0; hf < 2; ++hf) {
        const float* qp = qg + (size_t)(n0 + np + 4 * hf) * DIM + h * DK;
        #pragma unroll
        for (int d4 = 0; d4 < 4; ++d4) {
            const float4 qv = *(const float4*)(qp + d4 * 4);
            qreg[hf][d4 * 4 + 0] = qv.x; qreg[hf][d4 * 4 + 1] = qv.y;
            qreg[hf][d4 * 4 + 2] = qv.z; qreg[hf][d4 * 4 + 3] = qv.w;
        }
    }
    float waec[EDIM];
    #pragma unroll
    for (int e = 0; e < EDIM; ++e) waec[e] = Wae[e * HEADS + h] * LOG2E;
    const float baeh = bae[h] * LOG2E;

    float sl[2] = {0.f, 0.f};
    float accv[2][DK], accT[2][EDIM];
    #pragma unroll
    for (int hf = 0; hf < 2; ++hf) {
        #pragma unroll
        for (int d = 0; d < DK; ++d) accv[hf][d] = 0.f;
        #pragma unroll
        for (int e = 0; e < EDIM; ++e) accT[hf][e] = 0.f;
    }

    // --- prologue: stage chunk 0 directly into buffer 0 ---
    {
        const int mb = mb0;
        float* ef_n = smem;
        float* k_n  = smem + KV_OFF;
        float* v_n  = k_n + MR * KV_ROW;
        int*   mk_n = (int*)(smem + MK_OFF);
        #pragma unroll
        for (int r = 0; r < 2; ++r) {
            const int idx = t + 256 * r;
            const int nn = idx >> 6, mm = (idx >> 2) & 15, q4 = idx & 3;
            const float4 ev = *(const float4*)(ef + ((size_t)(n0 + nn) * NNODE + mb + mm) * EDIM + q4 * 4);
            *(float4*)&ef_n[nn * EF_NSTR + mm * EF_ROW + q4 * 4] = ev;
        }
        #pragma unroll
        for (int r = 0; r < 2; ++r) {
            const int idx = t + 256 * r;
            const int mm = idx >> 5, c4 = idx & 31;
            const int hh = c4 >> 2, d4 = c4 & 3;
            const float4 kq = *(const float4*)(kg + (size_t)(mb + mm) * DIM + c4 * 4);
            const float4 vq = *(const float4*)(vg + (size_t)(mb + mm) * DIM + c4 * 4);
            *(float4*)&k_n[mm * KV_ROW + hh * H_STRIDE + d4 * 4] = kq;
            *(float4*)&v_n[mm * KV_ROW + hh * H_STRIDE + d4 * 4] = vq;
        }
        if (t < BN * MR)
            mk_n[(t >> 4) * MK_STR + (t & 15)] = mask[(size_t)(n0 + (t >> 4)) * NNODE + (mb + (t & 15))];
    }
    __syncthreads();

    #pragma unroll 1
    for (int c = 0; c < NCH; ++c) {
        float* ef_c = smem + (c & 1) * BUF;
        float* k_c  = ef_c + KV_OFF;
        float* v_c  = k_c + MR * KV_ROW;
        int*   mk_c = (int*)(ef_c + MK_OFF);
        const bool pf = (c + 1 < NCH);

        // --- issue-early: global loads for chunk c+1 into registers ---
        float4 nef[2], nk[2], nv[2]; int nmk = 0;
        if (pf) {
            const int mb = mb0 + (c + 1) * MR;
            #pragma unroll
            for (int r = 0; r < 2; ++r) {
                const int idx = t + 256 * r;
                const int nn = idx >> 6, mm = (idx >> 2) & 15, q4 = idx & 3;
                nef[r] = *(const float4*)(ef + ((size_t)(n0 + nn) * NNODE + mb + mm) * EDIM + q4 * 4);
            }
            #pragma unroll
            for (int r = 0; r < 2; ++r) {
                const int idx = t + 256 * r;
                const int mm = idx >> 5, c4 = idx & 31;
                nk[r] = *(const float4*)(kg + (size_t)(mb + mm) * DIM + c4 * 4);
                nv[r] = *(const float4*)(vg + (size_t)(mb + mm) * DIM + c4 * 4);
            }
            if (t < BN * MR)
                nmk = mask[(size_t)(n0 + (t >> 4)) * NNODE + (mb + (t & 15))];
        }

        // --- compute chunk c from buf[c&1]; loads in flight above ---
        #pragma unroll
        for (int j = 0; j < 2; ++j) {
            const int m = j * 8 + s;
            float kk[DK], vv[DK];
            const float* kp = &k_c[m * KV_ROW + h * H_STRIDE];
            const float* vp = &v_c[m * KV_ROW + h * H_STRIDE];
            #pragma unroll
            for (int d4 = 0; d4 < 4; ++d4) {
                const float4 k4 = *(const float4*)(kp + d4 * 4);
                kk[d4 * 4 + 0] = k4.x; kk[d4 * 4 + 1] = k4.y;
                kk[d4 * 4 + 2] = k4.z; kk[d4 * 4 + 3] = k4.w;
                const float4 v4 = *(const float4*)(vp + d4 * 4);
                vv[d4 * 4 + 0] = v4.x; vv[d4 * 4 + 1] = v4.y;
                vv[d4 * 4 + 2] = v4.z; vv[d4 * 4 + 3] = v4.w;
            }
            #pragma unroll
            for (int hf = 0; hf < 2; ++hf) {
                const int n = np + 4 * hf;
                const float* ep = &ef_c[n * EF_NSTR + m * EF_ROW];
                float efv[EDIM];
                #pragma unroll
                for (int e4 = 0; e4 < 4; ++e4) {       // STATIC e4 (skew handles banks)
                    const float4 ev = *(const float4*)(ep + e4 * 4);
                    efv[e4 * 4 + 0] = ev.x; efv[e4 * 4 + 1] = ev.y;
                    efv[e4 * 4 + 2] = ev.z; efv[e4 * 4 + 3] = ev.w;
                }
                float bias = baeh, dot = 0.f;
                #pragma unroll
                for (int e = 0; e < EDIM; ++e) bias = fmaf(efv[e], waec[e], bias);
                #pragma unroll
                for (int d = 0; d < DK; ++d) dot = fmaf(qreg[hf][d], kk[d], dot);
                const float lg = fmaf(dot, 0.25f * LOG2E, bias);
                const float p = mk_c[n * MK_STR + m] ? __builtin_amdgcn_exp2f(lg) : 0.f;
                sl[hf] += p;
                #pragma unroll
                for (int d = 0; d < DK; ++d) accv[hf][d] = fmaf(p, vv[d], accv[hf][d]);
                #pragma unroll
                for (int e = 0; e < EDIM; ++e) accT[hf][e] = fmaf(p, efv[e], accT[hf][e]);
            }
        }

        // --- write-late: staged regs -> buf[(c+1)&1] ---
        if (pf) {
            float* ef_n = smem + ((c + 1) & 1) * BUF;
            float* k_n  = ef_n + KV_OFF;
            float* v_n  = k_n + MR * KV_ROW;
            int*   mk_n = (int*)(ef_n + MK_OFF);
            #pragma unroll
            for (int r = 0; r < 2; ++r) {
                const int idx = t + 256 * r;
                const int nn = idx >> 6, mm = (idx >> 2) & 15, q4 = idx & 3;
                *(float4*)&ef_n[nn * EF_NSTR + mm * EF_ROW + q4 * 4] = nef[r];
            }
            #pragma unroll
            for (int r = 0; r < 2; ++r) {
                const int idx = t + 256 * r;
                const int mm = idx >> 5, c4 = idx & 31;
                const int hh = c4 >> 2, d4 = c4 & 3;
                *(float4*)&k_n[mm * KV_ROW + hh * H_STRIDE + d4 * 4] = nk[r];
                *(float4*)&v_n[mm * KV_ROW + hh * H_STRIDE + d4 * 4] = nv[r];
            }
            if (t < BN * MR)
                mk_n[(t >> 4) * MK_STR + (t & 15)] = nmk;
        }
        __syncthreads();   // single barrier per chunk: publishes buf[(c+1)&1],
                           // and guards buf[c&1] reads vs iteration c+1's writes
    }

    // --- reduce s-pairs within wave (lane ^ 32) ---
    #pragma unroll
    for (int hf = 0; hf < 2; ++hf) {
        sl[hf] += __shfl_xor(sl[hf], 32);
        #pragma unroll
        for (int d = 0; d < DK; ++d) accv[hf][d] += __shfl_xor(accv[hf][d], 32);
        #pragma unroll
        for (int e = 0; e < EDIM; ++e) accT[hf][e] += __shfl_xor(accT[hf][e], 32);
    }
    // loop-end barrier already separates all LDS reads from the overlay below
    float* red = smem;               // [w4][np4][h8][hf2][33] = 8448 f32 overlay
    if (lane < 32) {
        float* rp = &red[((wid * 4 + np) * 8 + h) * 66];
        #pragma unroll
        for (int hf = 0; hf < 2; ++hf) {
            rp[hf * 33 + 0] = sl[hf];
            #pragma unroll
            for (int d = 0; d < DK; ++d) rp[hf * 33 + 1 + d] = accv[hf][d];
            #pragma unroll
            for (int e = 0; e < EDIM; ++e) rp[hf * 33 + 17 + e] = accT[hf][e];
        }
    }
    __syncthreads();
    // --- combine 4 wave copies, plain store to this block's group slot ---
    // acc layout: [n][grp][264]; each (n,grp) written by exactly one block.
    for (int v = t; v < BN * HEADS * 33; v += 256) {   // 2112 values
        const int n = v / 264;
        const int rem = v - n * 264;
        const int hh = rem / 33;
        const int idx = rem - hh * 33;
        const int nnp = n & 3, hf = n >> 2;
        float sum = 0.f;
        #pragma unroll
        for (int w = 0; w < 4; ++w)
            sum += red[((w * 4 + nnp) * 8 + hh) * 66 + hf * 33 + idx];
        acc[((size_t)(n0 + n) * NGRP + grp) * 264 + rem] = sum;
    }
}

// ---------------- Kernel 3: epilogue (sum groups, Wve, normalize, Wo, residual) ----------------
__global__ __launch_bounds__(128)
void final_kernel(const float* __restrict__ acc,
                  const float* __restrict__ Wve, const float* __restrict__ bve,
                  const float* __restrict__ x,
                  const float* __restrict__ Wo, const float* __restrict__ bo,
                  float* __restrict__ out) {
    const int n = blockIdx.x, t = threadIdx.x;
    __shared__ float ab[HEADS * 33];
    __shared__ float orow[DIM];
    const float* ap = acc + (size_t)n * NGRP * 264;
    for (int u = t; u < HEADS * 33; u += 128) {
        float sv = 0.f;
        #pragma unroll
        for (int g = 0; g < NGRP; ++g) sv += ap[g * 264 + u];
        ab[u] = sv;
    }
    __syncthreads();
    const int col = t, hh = col >> 4, dd = col & 15;
    const float slv = ab[hh * 33];
    float acc2 = 0.f;
    #pragma unroll
    for (int e = 0; e < EDIM; ++e) acc2 = fmaf(ab[hh * 33 + 17 + e], Wve[e * DIM + col], acc2);
    orow[col] = (ab[hh * 33 + 1 + dd] + acc2) / slv + bve[col];
    __syncthreads();
    float o0 = bo[col] + x[(size_t)n * DIM + col], o1 = 0.f;
    #pragma unroll 8
    for (int i = 0; i < DIM; i += 2) {
        o0 = fmaf(orow[i],     Wo[i * DIM + col],       o0);
        o1 = fmaf(orow[i + 1], Wo[(i + 1) * DIM + col], o1);
    }
    out[(size_t)n * DIM + col] = o0 + o1;
}

extern "C" void kernel_launch(void* const* d_in, const int* in_sizes, int n_in,
                              void* d_out, int out_size, void* d_ws, size_t ws_size,
                              hipStream_t stream) {
    const float* x     = (const float*)d_in[0];
    const float* ef    = (const float*)d_in[1];
    const int*   mask  = (const int*)d_in[2];
    const float* Wq    = (const float*)d_in[3];
    const float* bq    = (const float*)d_in[4];
    const float* Wk    = (const float*)d_in[5];
    const float* bk    = (const float*)d_in[6];
    const float* Wv    = (const float*)d_in[7];
    const float* bv    = (const float*)d_in[8];
    const float* Wae   = (const float*)d_in[9];
    const float* bae   = (const float*)d_in[10];
    const float* Wve   = (const float*)d_in[11];
    const float* bve   = (const float*)d_in[12];
    const float* Wo    = (const float*)d_in[13];
    const float* bo    = (const float*)d_in[14];
    const float* gamma = (const float*)d_in[15];
    const float* beta  = (const float*)d_in[16];

    float* ws = (float*)d_ws;
    float* accb = ws;                                   // 1024*8*264 f32
    float* qg   = ws + (size_t)NNODE * NGRP * 264;
    float* kg   = qg + (size_t)NNODE * DIM;
    float* vg   = kg + (size_t)NNODE * DIM;

    ln_qkv_kernel<<<NNODE, 384, 0, stream>>>(x, Wq, bq, Wk, bk, Wv, bv, gamma, beta, qg, kg, vg);
    attn_kernel<<<(NNODE / BN) * NGRP, 256, 0, stream>>>(qg, kg, vg, ef, mask, Wae, bae, accb);
    final_kernel<<<NNODE, 128, 0, stream>>>(accb, Wve, bve, x, Wo, bo, (float*)d_out);
}

// Round 4
// 172.627 us; speedup vs baseline: 1.4923x; 1.4923x over previous
//
#include <hip/hip_runtime.h>
#include <hip/hip_bf16.h>

#define NNODE 1024
#define DIM 128
#define HEADS 8
#define DK 16
#define EDIM 16
#define BN 8               // target nodes per attn block
#define NGRP 8             // m-group blocks per target row (128 rows each)
#define KV_ROW 160         // k/v LDS row stride dwords = 8 h * 20
#define H_STRIDE 20        // 20h mod 32 distinct for h=0..7 -> conflict-free reads
#define EF_ROW 20          // ef m-stride (dwords)
#define EFW_NSTR 104       // ef n-stride: 104=4*26, 26 mod 8 = 2 -> exactly-2-way writes (free), distinct-slot reads
#define LOG2E 1.44269504f

// per-WAVE private region (dwords): k [4][160] | v [4][160] | ef [8][104] | mk 32 ints
#define WREG 2176
#define VW_OFF 640
#define EFW_OFF 1280
#define MKW_OFF 2112
#define SMEM_F (4 * WREG)  // 8704 dw = 34816 B; reduction overlay 8448 dw fits

// ---------------- Kernel 1: LayerNorm + QKV projection ----------------
__global__ __launch_bounds__(384)
void ln_qkv_kernel(const float* __restrict__ x,
                   const float* __restrict__ Wq, const float* __restrict__ bq,
                   const float* __restrict__ Wk, const float* __restrict__ bk,
                   const float* __restrict__ Wv, const float* __restrict__ bv,
                   const float* __restrict__ gamma, const float* __restrict__ beta,
                   float* __restrict__ qg, float* __restrict__ kg, float* __restrict__ vg) {
    const int n = blockIdx.x;
    const int t = threadIdx.x;
    __shared__ float hrow[DIM];
    __shared__ float part[4];

    float xv = 0.f;
    if (t < 128) {
        xv = x[n * DIM + t];
        float v = xv;
        #pragma unroll
        for (int off = 32; off >= 1; off >>= 1) v += __shfl_xor(v, off);
        if ((t & 63) == 0) part[t >> 6] = v;
    }
    __syncthreads();
    const float mu = (part[0] + part[1]) * (1.0f / DIM);
    const float dx = xv - mu;
    if (t < 128) {
        float v = dx * dx;
        #pragma unroll
        for (int off = 32; off >= 1; off >>= 1) v += __shfl_xor(v, off);
        if ((t & 63) == 0) part[2 + (t >> 6)] = v;
    }
    __syncthreads();
    if (t < 128) {
        const float var = (part[2] + part[3]) * (1.0f / DIM);
        hrow[t] = dx * rsqrtf(var + 1e-5f) * gamma[t] + beta[t];
    }
    __syncthreads();

    const int which = t >> 7;          // 0,1,2 -> q,k,v (wave-uniform)
    const int col = t & 127;
    const float* W = (which == 0) ? Wq : (which == 1) ? Wk : Wv;
    const float* b = (which == 0) ? bq : (which == 1) ? bk : bv;
    float* o       = (which == 0) ? qg : (which == 1) ? kg : vg;
    float a0 = b[col], a1 = 0.f;       // dual accumulators: break 128-deep dep chain
    #pragma unroll 8
    for (int i = 0; i < DIM; i += 2) {
        a0 = fmaf(hrow[i],     W[i * DIM + col],       a0);
        a1 = fmaf(hrow[i + 1], W[(i + 1) * DIM + col], a1);
    }
    o[n * DIM + col] = a0 + a1;
}

// ---------------- Kernel 2: barrier-free wave-private chunked attention ----------------
// grid = (1024/BN) * NGRP = 1024 blocks; 256 threads (4 waves).
// Round-3 lesson: reg staging across compute spills (~115 persistent regs) -> 140MB
// scratch traffic. Round-2 lesson: barriered chunk loop lockstops all waves on
// vmcnt(0) drain every chunk (VALUBusy 25%). This round: NO barrier in the hot
// loop. Each WAVE owns a private 32-row m-range and a private LDS region; it
// stages 4 m-rows/iteration (global->reg->ds_write, short liveness) and computes
// from its own region. Waves free-run; a wave's staging latency hides under the
// other 3 waves/SIMD computing. Only the final reduction barriers remain.
// Lane map (per wave): sp = lane>>5 (m-sub pair), np = (lane>>3)&3, h = lane&7;
// lane computes m = sp*2+j (j=0,1) x n = np+4*hf (hf=0,1).
// ALL register-array indices are compile-time constants.
__global__ __launch_bounds__(256, 2)
void attn_kernel(const float* __restrict__ qg, const float* __restrict__ kg,
                 const float* __restrict__ vg, const float* __restrict__ ef,
                 const int* __restrict__ mask,
                 const float* __restrict__ Wae, const float* __restrict__ bae,
                 float* __restrict__ acc) {
    const int t = threadIdx.x;
    const int lane = t & 63;
    const int wid = t >> 6;
    const int sp = lane >> 5;     // 0,1: m sub-pair selector
    const int np = (lane >> 3) & 3;
    const int h  = lane & 7;
    const int bx = blockIdx.x;
    const int n0  = (bx >> 3) * BN;
    const int grp = bx & 7;
    const int mb_w = grp * 128 + wid * 32;   // this wave's private 32 source rows

    __shared__ float smem[SMEM_F];
    float* k_w  = smem + wid * WREG;         // [4][KV_ROW]
    float* v_w  = k_w + VW_OFF;              // [4][KV_ROW]
    float* ef_w = k_w + EFW_OFF;             // [8][EFW_NSTR]
    int*   mk_w = (int*)(k_w + MKW_OFF);     // [8][4]

    // --- per-thread constants (global, L2-hot) ---
    float qreg[2][DK];
    #pragma unroll
    for (int hf = 0; hf < 2; ++hf) {
        const float* qp = qg + (size_t)(n0 + np + 4 * hf) * DIM + h * DK;
        #pragma unroll
        for (int d4 = 0; d4 < 4; ++d4) {
            const float4 qv = *(const float4*)(qp + d4 * 4);
            qreg[hf][d4 * 4 + 0] = qv.x; qreg[hf][d4 * 4 + 1] = qv.y;
            qreg[hf][d4 * 4 + 2] = qv.z; qreg[hf][d4 * 4 + 3] = qv.w;
        }
    }
    float waec[EDIM];
    #pragma unroll
    for (int e = 0; e < EDIM; ++e) waec[e] = Wae[e * HEADS + h] * LOG2E;
    const float baeh = bae[h] * LOG2E;

    float sl[2] = {0.f, 0.f};
    float accv[2][DK], accT[2][EDIM];
    #pragma unroll
    for (int hf = 0; hf < 2; ++hf) {
        #pragma unroll
        for (int d = 0; d < DK; ++d) accv[hf][d] = 0.f;
        #pragma unroll
        for (int e = 0; e < EDIM; ++e) accT[hf][e] = 0.f;
    }

    #pragma unroll 1
    for (int c = 0; c < 8; ++c) {
        const int mb = mb_w + c * 4;         // 4 m-rows this iteration

        // --- stage: issue ALL global loads first (in flight together), then ds_write.
        //     Liveness is a few instructions -> no spill. No barrier: region is
        //     wave-private; DS ops are wave-ordered, compiler inserts lgkm waits.
        const int kvrow = sp * 2 + (np >> 1);        // lane -> one of 4 rows
        const int kvc4  = (np & 1) * 16 + (h << 1);  // hmm -- see simple map below
        // simple r-loop map identical to round 2's (idx = 64r + lane):
        float4 kq[2], vq[2], ev[2]; int mki = 0;
        #pragma unroll
        for (int r = 0; r < 2; ++r) {
            const int idx = r * 64 + lane;           // 0..127 16B-chunks
            const int row = idx >> 5, c4 = idx & 31;
            kq[r] = *(const float4*)(kg + (size_t)(mb + row) * DIM + c4 * 4);
            vq[r] = *(const float4*)(vg + (size_t)(mb + row) * DIM + c4 * 4);
        }
        #pragma unroll
        for (int r = 0; r < 2; ++r) {
            const int idx = r * 64 + lane;           // 0..127
            const int nn = idx >> 4, mm = (idx >> 2) & 3, q4 = idx & 3;
            ev[r] = *(const float4*)(ef + ((size_t)(n0 + nn) * NNODE + mb + mm) * EDIM + q4 * 4);
        }
        if (lane < 32)
            mki = mask[(size_t)(n0 + (lane >> 2)) * NNODE + (mb + (lane & 3))];
        #pragma unroll
        for (int r = 0; r < 2; ++r) {
            const int idx = r * 64 + lane;
            const int row = idx >> 5, c4 = idx & 31;
            const int hh = c4 >> 2, d4 = c4 & 3;
            *(float4*)&k_w[row * KV_ROW + hh * H_STRIDE + d4 * 4] = kq[r];
            *(float4*)&v_w[row * KV_ROW + hh * H_STRIDE + d4 * 4] = vq[r];
        }
        #pragma unroll
        for (int r = 0; r < 2; ++r) {
            const int idx = r * 64 + lane;
            const int nn = idx >> 4, mm = (idx >> 2) & 3, q4 = idx & 3;
            *(float4*)&ef_w[nn * EFW_NSTR + mm * EF_ROW + q4 * 4] = ev[r];
        }
        if (lane < 32)
            mk_w[lane] = mki;                        // [nn][mm] = lane>>2, lane&3

        // --- compute: 2 m per lane (ml = sp*2+j), n-pair per m; all indices static ---
        #pragma unroll
        for (int j = 0; j < 2; ++j) {
            const int ml = sp * 2 + j;
            float kk[DK], vv[DK];
            const float* kp = &k_w[ml * KV_ROW + h * H_STRIDE];
            const float* vp = &v_w[ml * KV_ROW + h * H_STRIDE];
            #pragma unroll
            for (int d4 = 0; d4 < 4; ++d4) {
                const float4 k4 = *(const float4*)(kp + d4 * 4);
                kk[d4 * 4 + 0] = k4.x; kk[d4 * 4 + 1] = k4.y;
                kk[d4 * 4 + 2] = k4.z; kk[d4 * 4 + 3] = k4.w;
                const float4 v4 = *(const float4*)(vp + d4 * 4);
                vv[d4 * 4 + 0] = v4.x; vv[d4 * 4 + 1] = v4.y;
                vv[d4 * 4 + 2] = v4.z; vv[d4 * 4 + 3] = v4.w;
            }
            #pragma unroll
            for (int hf = 0; hf < 2; ++hf) {
                const int n = np + 4 * hf;
                const float* ep = &ef_w[n * EFW_NSTR + ml * EF_ROW];
                float efv[EDIM];
                #pragma unroll
                for (int e4 = 0; e4 < 4; ++e4) {      // STATIC e4 (stride algebra handles banks)
                    const float4 e4v = *(const float4*)(ep + e4 * 4);
                    efv[e4 * 4 + 0] = e4v.x; efv[e4 * 4 + 1] = e4v.y;
                    efv[e4 * 4 + 2] = e4v.z; efv[e4 * 4 + 3] = e4v.w;
                }
                float bias = baeh, dot = 0.f;
                #pragma unroll
                for (int e = 0; e < EDIM; ++e) bias = fmaf(efv[e], waec[e], bias);
                #pragma unroll
                for (int d = 0; d < DK; ++d) dot = fmaf(qreg[hf][d], kk[d], dot);
                const float lg = fmaf(dot, 0.25f * LOG2E, bias);
                const float p = mk_w[n * 4 + ml] ? __builtin_amdgcn_exp2f(lg) : 0.f;
                sl[hf] += p;
                #pragma unroll
                for (int d = 0; d < DK; ++d) accv[hf][d] = fmaf(p, vv[d], accv[hf][d]);
                #pragma unroll
                for (int e = 0; e < EDIM; ++e) accT[hf][e] = fmaf(p, efv[e], accT[hf][e]);
            }
        }
    }

    // --- reduce sp-pairs within wave (lane ^ 32): combines the two m-subsets ---
    #pragma unroll
    for (int hf = 0; hf < 2; ++hf) {
        sl[hf] += __shfl_xor(sl[hf], 32);
        #pragma unroll
        for (int d = 0; d < DK; ++d) accv[hf][d] += __shfl_xor(accv[hf][d], 32);
        #pragma unroll
        for (int e = 0; e < EDIM; ++e) accT[hf][e] += __shfl_xor(accT[hf][e], 32);
    }
    __syncthreads();                 // all waves done with private regions -> overlay
    float* red = smem;               // [w4][np4][h8][hf2][33] = 8448 f32 overlay
    if (lane < 32) {
        float* rp = &red[((wid * 4 + np) * 8 + h) * 66];
        #pragma unroll
        for (int hf = 0; hf < 2; ++hf) {
            rp[hf * 33 + 0] = sl[hf];
            #pragma unroll
            for (int d = 0; d < DK; ++d) rp[hf * 33 + 1 + d] = accv[hf][d];
            #pragma unroll
            for (int e = 0; e < EDIM; ++e) rp[hf * 33 + 17 + e] = accT[hf][e];
        }
    }
    __syncthreads();
    // --- combine 4 wave copies, plain store to this block's group slot ---
    // acc layout: [n][grp][264]; each (n,grp) written by exactly one block.
    for (int v = t; v < BN * HEADS * 33; v += 256) {   // 2112 values
        const int n = v / 264;
        const int rem = v - n * 264;
        const int hh = rem / 33;
        const int idx = rem - hh * 33;
        const int nnp = n & 3, hf = n >> 2;
        float sum = 0.f;
        #pragma unroll
        for (int w = 0; w < 4; ++w)
            sum += red[((w * 4 + nnp) * 8 + hh) * 66 + hf * 33 + idx];
        acc[((size_t)(n0 + n) * NGRP + grp) * 264 + rem] = sum;
    }
}

// ---------------- Kernel 3: epilogue (sum groups, Wve, normalize, Wo, residual) ----------------
__global__ __launch_bounds__(128)
void final_kernel(const float* __restrict__ acc,
                  const float* __restrict__ Wve, const float* __restrict__ bve,
                  const float* __restrict__ x,
                  const float* __restrict__ Wo, const float* __restrict__ bo,
                  float* __restrict__ out) {
    const int n = blockIdx.x, t = threadIdx.x;
    __shared__ float ab[HEADS * 33];
    __shared__ float orow[DIM];
    const float* ap = acc + (size_t)n * NGRP * 264;
    for (int u = t; u < HEADS * 33; u += 128) {
        float sv = 0.f;
        #pragma unroll
        for (int g = 0; g < NGRP; ++g) sv += ap[g * 264 + u];
        ab[u] = sv;
    }
    __syncthreads();
    const int col = t, hh = col >> 4, dd = col & 15;
    const float slv = ab[hh * 33];
    float acc2 = 0.f;
    #pragma unroll
    for (int e = 0; e < EDIM; ++e) acc2 = fmaf(ab[hh * 33 + 17 + e], Wve[e * DIM + col], acc2);
    orow[col] = (ab[hh * 33 + 1 + dd] + acc2) / slv + bve[col];
    __syncthreads();
    float o0 = bo[col] + x[(size_t)n * DIM + col], o1 = 0.f;
    #pragma unroll 8
    for (int i = 0; i < DIM; i += 2) {
        o0 = fmaf(orow[i],     Wo[i * DIM + col],       o0);
        o1 = fmaf(orow[i + 1], Wo[(i + 1) * DIM + col], o1);
    }
    out[(size_t)n * DIM + col] = o0 + o1;
}

extern "C" void kernel_launch(void* const* d_in, const int* in_sizes, int n_in,
                              void* d_out, int out_size, void* d_ws, size_t ws_size,
                              hipStream_t stream) {
    const float* x     = (const float*)d_in[0];
    const float* ef    = (const float*)d_in[1];
    const int*   mask  = (const int*)d_in[2];
    const float* Wq    = (const float*)d_in[3];
    const float* bq    = (const float*)d_in[4];
    const float* Wk    = (const float*)d_in[5];
    const float* bk    = (const float*)d_in[6];
    const float* Wv    = (const float*)d_in[7];
    const float* bv    = (const float*)d_in[8];
    const float* Wae   = (const float*)d_in[9];
    const float* bae   = (const float*)d_in[10];
    const float* Wve   = (const float*)d_in[11];
    const float* bve   = (const float*)d_in[12];
    const float* Wo    = (const float*)d_in[13];
    const float* bo    = (const float*)d_in[14];
    const float* gamma = (const float*)d_in[15];
    const float* beta  = (const float*)d_in[16];

    float* ws = (float*)d_ws;
    float* accb = ws;                                   // 1024*8*264 f32
    float* qg   = ws + (size_t)NNODE * NGRP * 264;
    float* kg   = qg + (size_t)NNODE * DIM;
    float* vg   = kg + (size_t)NNODE * DIM;

    ln_qkv_kernel<<<NNODE, 384, 0, stream>>>(x, Wq, bq, Wk, bk, Wv, bv, gamma, beta, qg, kg, vg);
    attn_kernel<<<(NNODE / BN) * NGRP, 256, 0, stream>>>(qg, kg, vg, ef, mask, Wae, bae, accb);
    final_kernel<<<NNODE, 128, 0, stream>>>(accb, Wve, bve, x, Wo, bo, (float*)d_out);
}